// Round 5
// baseline (505.266 us; speedup 1.0000x reference)
//
#include <hip/hip_runtime.h>
#include <stdint.h>

#define DIM 256
#define NPOS 4096
#define NB 4
#define GROUPS 32

typedef __attribute__((ext_vector_type(8))) short short8;
typedef __attribute__((ext_vector_type(4))) short short4v;
typedef __attribute__((ext_vector_type(4))) float f32x4;
typedef __attribute__((ext_vector_type(2))) unsigned int u32x2;

__device__ __forceinline__ short f2b(float f) {
  unsigned u = __float_as_uint(f);
  unsigned r = (u + 0x7fffu + ((u >> 16) & 1u)) >> 16;
  return (short)r;
}

// ---------------- weight conversion (f32 -> bf16) ----------------
__global__ void k_convert_w(const float* __restrict__ wq, const float* __restrict__ wp,
                            short* __restrict__ wqb, short* __restrict__ wpb) {
  int i = blockIdx.x * 256 + threadIdx.x;
  if (i < 768 * 256) wqb[i] = f2b(wq[i]);
  if (i < 256 * 256) wpb[i] = f2b(wp[i]);
}

// ---------------- GroupNorm stats: one block per (b,g) ----------------
__global__ void k_gn_stats(const float* __restrict__ x, float* __restrict__ stats) {
  int bg = blockIdx.x;
  const float4* b4 = (const float4*)(x + (size_t)bg * 8 * NPOS);
  float s = 0.f, ss = 0.f;
  for (int i = threadIdx.x; i < 8192; i += 256) {
    float4 v = b4[i];
    s  += v.x + v.y + v.z + v.w;
    ss += v.x * v.x + v.y * v.y + v.z * v.z + v.w * v.w;
  }
  #pragma unroll
  for (int m = 1; m < 64; m <<= 1) { s += __shfl_xor(s, m, 64); ss += __shfl_xor(ss, m, 64); }
  __shared__ float red[8];
  int wid = threadIdx.x >> 6;
  if ((threadIdx.x & 63) == 0) { red[wid * 2] = s; red[wid * 2 + 1] = ss; }
  __syncthreads();
  if (threadIdx.x == 0) {
    float S = red[0] + red[2] + red[4] + red[6];
    float SS = red[1] + red[3] + red[5] + red[7];
    float mean = S / 32768.f;
    float var = SS / 32768.f - mean * mean;
    stats[bg * 2] = mean;
    stats[bg * 2 + 1] = rsqrtf(var + 1e-6f);
  }
}

// ------------- GroupNorm apply + transpose: x(B,C,N) f32 -> h_t(B,N,C) bf16 -------------
__global__ void k_gn_apply(const float* __restrict__ x, const float* __restrict__ stats,
                           const float* __restrict__ gamma, const float* __restrict__ beta,
                           short* __restrict__ ht) {
  int ct = blockIdx.x, nt = blockIdx.y, b = blockIdx.z;
  int c0 = ct * 64, n0 = nt * 64;
  __shared__ short lt[64 * 72];
  int t = threadIdx.x;
  #pragma unroll
  for (int p = 0; p < 4; ++p) {
    int row = (t >> 4) + p * 16;
    int colb = (t & 15) * 4;
    int c = c0 + row;
    float mean = stats[(b * GROUPS + (c >> 3)) * 2];
    float rstd = stats[(b * GROUPS + (c >> 3)) * 2 + 1];
    float ga = gamma[c], be = beta[c];
    float4 v = *(const float4*)(x + ((size_t)(b * DIM + c)) * NPOS + n0 + colb);
    short4v o;
    o.x = f2b((v.x - mean) * rstd * ga + be);
    o.y = f2b((v.y - mean) * rstd * ga + be);
    o.z = f2b((v.z - mean) * rstd * ga + be);
    o.w = f2b((v.w - mean) * rstd * ga + be);
    *(short4v*)&lt[row * 72 + colb] = o;
  }
  __syncthreads();
  #pragma unroll
  for (int p = 0; p < 2; ++p) {
    int nr = (t >> 3) + p * 32;
    int ch = t & 7;
    short8 o;
    #pragma unroll
    for (int j = 0; j < 8; ++j) o[j] = lt[(ch * 8 + j) * 72 + nr];
    *(short8*)(ht + ((size_t)(b * NPOS + n0 + nr)) * DIM + c0 + ch * 8) = o;
  }
}

// ---------------- gemm_bt: C[M,N] = A[M,K] * B[N,K]^T, K=256, 128x128 tile ----------------
template <int MODE>
__launch_bounds__(256, 2)
__global__ void k_gemm(const short* __restrict__ A, const short* __restrict__ Bm,
                       const float* __restrict__ bias,
                       short* __restrict__ qb, short* __restrict__ kb, short* __restrict__ vtb,
                       const float* __restrict__ resid, float* __restrict__ outf) {
  const int K = 256;
  int b = blockIdx.z;
  int m0 = blockIdx.x * 128, n0 = blockIdx.y * 128;
  const short* Ap = (MODE == 0) ? A + (size_t)b * NPOS * K : A;
  const short* Bp = (MODE == 0) ? Bm : Bm + (size_t)b * NPOS * K;

  __shared__ short As[128 * 64], Bs[128 * 64];
  int t = threadIdx.x;
  int lane = t & 63, wid = t >> 6;
  int wm = wid >> 1, wn = wid & 1;
  f32x4 acc[4][4] = {};

  for (int kt = 0; kt < 4; ++kt) {
    int k0 = kt * 64;
    short8 av[4], bv[4];
    #pragma unroll
    for (int p = 0; p < 4; ++p) {
      int ci = t + p * 256;
      int row = ci >> 3, ch = ci & 7;
      av[p] = *(const short8*)(Ap + (size_t)(m0 + row) * K + k0 + ch * 8);
      bv[p] = *(const short8*)(Bp + (size_t)(n0 + row) * K + k0 + ch * 8);
    }
    __syncthreads();
    #pragma unroll
    for (int p = 0; p < 4; ++p) {
      int ci = t + p * 256;
      int row = ci >> 3, ch = ci & 7;
      int off = (row * 128 + ch * 16) ^ ((row & 7) << 4);
      *(short8*)((char*)As + off) = av[p];
      *(short8*)((char*)Bs + off) = bv[p];
    }
    __syncthreads();
    #pragma unroll
    for (int ks = 0; ks < 2; ++ks) {
      short8 af[4], bf[4];
      int inner = ks * 64 + (lane >> 4) * 16;
      #pragma unroll
      for (int mi = 0; mi < 4; ++mi) {
        int row = wm * 64 + mi * 16 + (lane & 15);
        af[mi] = *(short8*)((char*)As + ((row * 128 + inner) ^ ((row & 7) << 4)));
      }
      #pragma unroll
      for (int ni = 0; ni < 4; ++ni) {
        int row = wn * 64 + ni * 16 + (lane & 15);
        bf[ni] = *(short8*)((char*)Bs + ((row * 128 + inner) ^ ((row & 7) << 4)));
      }
      #pragma unroll
      for (int mi = 0; mi < 4; ++mi)
        #pragma unroll
        for (int ni = 0; ni < 4; ++ni)
          acc[mi][ni] = __builtin_amdgcn_mfma_f32_16x16x32_bf16(af[mi], bf[ni], acc[mi][ni], 0, 0, 0);
    }
  }

  #pragma unroll
  for (int mi = 0; mi < 4; ++mi)
    #pragma unroll
    for (int ni = 0; ni < 4; ++ni) {
      int gcol = n0 + wn * 64 + ni * 16 + (lane & 15);
      #pragma unroll
      for (int r = 0; r < 4; ++r) {
        int grow = m0 + wm * 64 + mi * 16 + (lane >> 4) * 4 + r;
        if (MODE == 0) {
          float v = acc[mi][ni][r] + bias[gcol];
          short h = f2b(v);
          if (gcol < 256)       qb[((size_t)b * NPOS + grow) * DIM + gcol] = h;
          else if (gcol < 512)  kb[((size_t)b * NPOS + grow) * DIM + gcol - 256] = h;
          else                  vtb[((size_t)b * DIM + gcol - 512) * NPOS + grow] = h;
        } else {
          float v = acc[mi][ni][r] + bias[grow];
          size_t idx = ((size_t)b * DIM + grow) * NPOS + gcol;
          outf[idx] = v + resid[idx];
        }
      }
    }
}

// ---- flash attention v4: NO K/V LDS — global->VGPR direct (KV is L2-resident, 4MB/batch).
// 4 waves = 2 q-subtiles(16 rows) x 2 kv-halves(2048), KVBLK=32, no main-loop barriers.
// Swapped QK^T (mfma(K,Q) -> S^T): softmax in-lane; P via cvt_pk -> wave-private LDS.
// LDS (37376 B): P@0 (4x1024), lm@4096 (512B), scratch@4608 (2x16KB f32).
__launch_bounds__(256, 2)
__global__ void k_flash(const short* __restrict__ qb, const short* __restrict__ kb,
                        const short* __restrict__ vtb, short* __restrict__ ob) {
  __shared__ __align__(16) char smem[37376];
  float* lm = (float*)(smem + 4096);
  float* scratch = (float*)(smem + 4608);

  // XCD-aware decode: xcd = i&7 -> batch b = xcd>>1 (one batch's KV per L2 pair)
  int i = blockIdx.x;
  int xcd = i & 7, slot = i >> 3;
  int b = xcd >> 1;
  int bx = slot * 2 + (xcd & 1);   // 0..127
  int q0 = bx * 32;

  int t = threadIdx.x, lane = t & 63, g = lane >> 4, wid = t >> 6;
  int qs = wid & 1, h = wid >> 1;

  const short* kbB = kb + (size_t)b * NPOS * DIM;
  const short* vbB = vtb + (size_t)b * DIM * NPOS;

  // ---- Q fragments (B-operand of swapped QK^T), pre-scaled by 1/16 (exact) ----
  short8 qf[8];
  {
    int qrow = q0 + qs * 16 + (lane & 15);
    const short* qp = qb + ((size_t)b * NPOS + qrow) * DIM + g * 8;
    #pragma unroll
    for (int s = 0; s < 8; ++s) {
      short8 v = *(const short8*)(qp + s * 32);
      #pragma unroll
      for (int j = 0; j < 8; ++j) {
        float f = __uint_as_float(((unsigned)(unsigned short)v[j]) << 16) * 0.0625f;
        v[j] = f2b(f);
      }
      qf[s] = v;
    }
  }

  // per-lane global bases: K frag row = lane&15, col chunk = g*8
  const short* kL = kbB + ((size_t)(h * 2048 + (lane & 15))) * DIM + g * 8;
  const short* vL = vbB + ((size_t)(lane & 15)) * NPOS + h * 2048 + g * 8;
  char* prow = smem + wid * 1024 + (lane & 15) * 64;

  f32x4 oacc[16] = {};
  float m = -1e30f, l = 0.f;

  const int NIT = 64;
  for (int it = 0; it < NIT; ++it) {
    int kv0 = it * 32;

    // ---- K fragments: 16x ds-free global loads (L2/L1-served) ----
    short8 kf[2][8];
    #pragma unroll
    for (int t2 = 0; t2 < 2; ++t2)
      #pragma unroll
      for (int s = 0; s < 8; ++s)
        kf[t2][s] = *(const short8*)(kL + (size_t)(kv0 + t2 * 16) * DIM + s * 32);

    // ---- V fragments issued early: latency hides under QK^T + softmax ----
    short8 vf[16];
    #pragma unroll
    for (int nt = 0; nt < 16; ++nt)
      vf[nt] = *(const short8*)(vL + (size_t)(nt * 16) * NPOS + kv0);

    // ---- QK^T (swapped): S^T[32kv x 16q], scale folded into Q ----
    f32x4 sacc[2] = {};
    #pragma unroll
    for (int s = 0; s < 8; ++s) {
      #pragma unroll
      for (int t2 = 0; t2 < 2; ++t2)
        sacc[t2] = __builtin_amdgcn_mfma_f32_16x16x32_bf16(kf[t2][s], qf[s], sacc[t2], 0, 0, 0);
    }

    // ---- online softmax, in-lane (q = lane&15), defer-max THR=8 ----
    float mx = fmaxf(fmaxf(fmaxf(sacc[0][0], sacc[0][1]), fmaxf(sacc[0][2], sacc[0][3])),
                     fmaxf(fmaxf(sacc[1][0], sacc[1][1]), fmaxf(sacc[1][2], sacc[1][3])));
    mx = fmaxf(mx, __shfl_xor(mx, 16, 64));
    mx = fmaxf(mx, __shfl_xor(mx, 32, 64));
    if (!__all(mx <= m + 8.f)) {
      float mn = fmaxf(m, mx);
      float al = __expf(m - mn);
      m = mn; l *= al;
      #pragma unroll
      for (int r = 0; r < 4; ++r) {
        float ar = __shfl(al, (lane & 48) + ((lane & 48) >> 2) + r, 64);
        #pragma unroll
        for (int nt = 0; nt < 16; ++nt) oacc[nt][r] *= ar;
      }
    }
    float p0 = __expf(sacc[0][0] - m), p1 = __expf(sacc[0][1] - m);
    float p2 = __expf(sacc[0][2] - m), p3 = __expf(sacc[0][3] - m);
    float p4 = __expf(sacc[1][0] - m), p5 = __expf(sacc[1][1] - m);
    float p6 = __expf(sacc[1][2] - m), p7 = __expf(sacc[1][3] - m);
    float ts = ((p0 + p1) + (p2 + p3)) + ((p4 + p5) + (p6 + p7));
    ts += __shfl_xor(ts, 16, 64);
    ts += __shfl_xor(ts, 32, 64);
    l += ts;

    // ---- P -> bf16, wave-private LDS (same elem type as load: short) ----
    unsigned w0, w1, w2, w3;
    asm("v_cvt_pk_bf16_f32 %0, %1, %2" : "=v"(w0) : "v"(p0), "v"(p1));
    asm("v_cvt_pk_bf16_f32 %0, %1, %2" : "=v"(w1) : "v"(p2), "v"(p3));
    asm("v_cvt_pk_bf16_f32 %0, %1, %2" : "=v"(w2) : "v"(p4), "v"(p5));
    asm("v_cvt_pk_bf16_f32 %0, %1, %2" : "=v"(w3) : "v"(p6), "v"(p7));
    *(short4v*)(prow + g * 8)      = __builtin_bit_cast(short4v, (u32x2){w0, w1});
    *(short4v*)(prow + 32 + g * 8) = __builtin_bit_cast(short4v, (u32x2){w2, w3});
    asm volatile("" ::: "memory");   // pin P stores before the pa load

    // ---- PV: O[16q x 256d] += P[16q x 32kv] * V[32kv x 256d] ----
    short8 pa = *(short8*)(prow + g * 16);
    #pragma unroll
    for (int nt = 0; nt < 16; ++nt)
      oacc[nt] = __builtin_amdgcn_mfma_f32_16x16x32_bf16(pa, vf[nt], oacc[nt], 0, 0, 0);
  }

  // ---- combine the two kv-halves (per q-subtile) ----
  __syncthreads();
  if (lane < 16) { lm[wid * 32 + lane * 2] = m; lm[wid * 32 + lane * 2 + 1] = l; }
  __syncthreads();
  int pw = wid ^ 2;
  float mo = lm[pw * 32 + (lane & 15) * 2];
  float lo = lm[pw * 32 + (lane & 15) * 2 + 1];
  float M = fmaxf(m, mo);
  float al = __expf(m - M);
  float Lf = l * al + lo * __expf(mo - M);
  float alr[4], iLr[4];
  #pragma unroll
  for (int r = 0; r < 4; ++r) {
    int src = (lane & 48) + ((lane & 48) >> 2) + r;
    alr[r] = __shfl(al, src, 64);
    iLr[r] = 1.f / __shfl(Lf, src, 64);
  }
  if (h == 0) {
    float* sc = scratch + qs * 4096;
    #pragma unroll
    for (int nt = 0; nt < 16; ++nt)
      #pragma unroll
      for (int r = 0; r < 4; ++r) {
        int q = 4 * g + r;
        int col = nt * 16 + (lane & 15);
        sc[(q * 256 + col) ^ ((g & 1) << 4)] = oacc[nt][r] * alr[r];
      }
  }
  __syncthreads();
  if (h == 1) {
    float* sc = scratch + qs * 4096;
    #pragma unroll
    for (int nt = 0; nt < 16; ++nt)
      #pragma unroll
      for (int r = 0; r < 4; ++r) {
        int q = 4 * g + r;
        int col = nt * 16 + (lane & 15);
        float v = (sc[(q * 256 + col) ^ ((g & 1) << 4)] + oacc[nt][r] * alr[r]) * iLr[r];
        ob[((size_t)b * NPOS + q0 + qs * 16 + q) * DIM + col] = f2b(v);
      }
  }
}

extern "C" void kernel_launch(void* const* d_in, const int* in_sizes, int n_in,
                              void* d_out, int out_size, void* d_ws, size_t ws_size,
                              hipStream_t stream) {
  const float* x     = (const float*)d_in[0];
  const float* gamma = (const float*)d_in[1];
  const float* beta  = (const float*)d_in[2];
  const float* wqkv  = (const float*)d_in[3];
  const float* bqkv  = (const float*)d_in[4];
  const float* wproj = (const float*)d_in[5];
  const float* bproj = (const float*)d_in[6];
  float* out = (float*)d_out;

  char* ws = (char*)d_ws;
  float* stats = (float*)ws;
  short* wqb = (short*)(ws + 1024);
  short* wpb = (short*)(ws + 1024 + 393216);
  size_t off = 1024 + 393216 + 131072;
  const size_t SZ = (size_t)NB * NPOS * DIM * sizeof(short);  // 8 MB
  short* ht   = (short*)(ws + off); off += SZ;
  short* qbuf = (short*)(ws + off); off += SZ;
  short* kbuf = (short*)(ws + off); off += SZ;
  short* vtb  = (short*)(ws + off); off += SZ;
  short* obuf = ht;  // h_t dead after QKV gemm; reuse for attention output

  k_convert_w<<<768, 256, 0, stream>>>(wqkv, wproj, wqb, wpb);
  k_gn_stats<<<128, 256, 0, stream>>>(x, stats);
  k_gn_apply<<<dim3(4, 64, NB), 256, 0, stream>>>(x, stats, gamma, beta, ht);
  k_gemm<0><<<dim3(32, 6, NB), 256, 0, stream>>>(ht, wqb, bqkv, qbuf, kbuf, vtb, nullptr, nullptr);
  k_flash<<<dim3(512), 256, 0, stream>>>(qbuf, kbuf, vtb, obuf);
  k_gemm<1><<<dim3(2, 32, NB), 256, 0, stream>>>(wpb, obuf, bproj, nullptr, nullptr, nullptr, x, out);
}

// Round 6
// 200.518 us; speedup vs baseline: 2.5198x; 2.5198x over previous
//
#include <hip/hip_runtime.h>
#include <stdint.h>

#define DIM 256
#define NPOS 4096
#define NB 4
#define GROUPS 32

typedef __attribute__((ext_vector_type(8))) short short8;
typedef __attribute__((ext_vector_type(4))) short short4v;
typedef __attribute__((ext_vector_type(4))) float f32x4;
typedef __attribute__((ext_vector_type(2))) unsigned int u32x2;

__device__ __forceinline__ short f2b(float f) {
  unsigned u = __float_as_uint(f);
  unsigned r = (u + 0x7fffu + ((u >> 16) & 1u)) >> 16;
  return (short)r;
}

__device__ __forceinline__ void gl16(const short* g, char* lds) {
  __builtin_amdgcn_global_load_lds((const __attribute__((address_space(1))) void*)g,
                                   (__attribute__((address_space(3))) void*)lds, 16, 0, 0);
}

// ---------------- weight conversion (f32 -> bf16) ----------------
__global__ void k_convert_w(const float* __restrict__ wq, const float* __restrict__ wp,
                            short* __restrict__ wqb, short* __restrict__ wpb) {
  int i = blockIdx.x * 256 + threadIdx.x;
  if (i < 768 * 256) wqb[i] = f2b(wq[i]);
  if (i < 256 * 256) wpb[i] = f2b(wp[i]);
}

// ---------------- GroupNorm stats: one block per (b,g) ----------------
__global__ void k_gn_stats(const float* __restrict__ x, float* __restrict__ stats) {
  int bg = blockIdx.x;
  const float4* b4 = (const float4*)(x + (size_t)bg * 8 * NPOS);
  float s = 0.f, ss = 0.f;
  for (int i = threadIdx.x; i < 8192; i += 256) {
    float4 v = b4[i];
    s  += v.x + v.y + v.z + v.w;
    ss += v.x * v.x + v.y * v.y + v.z * v.z + v.w * v.w;
  }
  #pragma unroll
  for (int m = 1; m < 64; m <<= 1) { s += __shfl_xor(s, m, 64); ss += __shfl_xor(ss, m, 64); }
  __shared__ float red[8];
  int wid = threadIdx.x >> 6;
  if ((threadIdx.x & 63) == 0) { red[wid * 2] = s; red[wid * 2 + 1] = ss; }
  __syncthreads();
  if (threadIdx.x == 0) {
    float S = red[0] + red[2] + red[4] + red[6];
    float SS = red[1] + red[3] + red[5] + red[7];
    float mean = S / 32768.f;
    float var = SS / 32768.f - mean * mean;
    stats[bg * 2] = mean;
    stats[bg * 2 + 1] = rsqrtf(var + 1e-6f);
  }
}

// ------------- GroupNorm apply + transpose: x(B,C,N) f32 -> h_t(B,N,C) bf16 -------------
__global__ void k_gn_apply(const float* __restrict__ x, const float* __restrict__ stats,
                           const float* __restrict__ gamma, const float* __restrict__ beta,
                           short* __restrict__ ht) {
  int ct = blockIdx.x, nt = blockIdx.y, b = blockIdx.z;
  int c0 = ct * 64, n0 = nt * 64;
  __shared__ short lt[64 * 72];
  int t = threadIdx.x;
  #pragma unroll
  for (int p = 0; p < 4; ++p) {
    int row = (t >> 4) + p * 16;
    int colb = (t & 15) * 4;
    int c = c0 + row;
    float mean = stats[(b * GROUPS + (c >> 3)) * 2];
    float rstd = stats[(b * GROUPS + (c >> 3)) * 2 + 1];
    float ga = gamma[c], be = beta[c];
    float4 v = *(const float4*)(x + ((size_t)(b * DIM + c)) * NPOS + n0 + colb);
    short4v o;
    o.x = f2b((v.x - mean) * rstd * ga + be);
    o.y = f2b((v.y - mean) * rstd * ga + be);
    o.z = f2b((v.z - mean) * rstd * ga + be);
    o.w = f2b((v.w - mean) * rstd * ga + be);
    *(short4v*)&lt[row * 72 + colb] = o;
  }
  __syncthreads();
  #pragma unroll
  for (int p = 0; p < 2; ++p) {
    int nr = (t >> 3) + p * 32;
    int ch = t & 7;
    short8 o;
    #pragma unroll
    for (int j = 0; j < 8; ++j) o[j] = lt[(ch * 8 + j) * 72 + nr];
    *(short8*)(ht + ((size_t)(b * NPOS + n0 + nr)) * DIM + c0 + ch * 8) = o;
  }
}

// ---------------- gemm_bt: C[M,N] = A[M,K] * B[N,K]^T, K=256, 128x128 tile ----------------
template <int MODE>
__launch_bounds__(256, 2)
__global__ void k_gemm(const short* __restrict__ A, const short* __restrict__ Bm,
                       const float* __restrict__ bias,
                       short* __restrict__ qb, short* __restrict__ kb, short* __restrict__ vtb,
                       const float* __restrict__ resid, float* __restrict__ outf) {
  const int K = 256;
  int b = blockIdx.z;
  int m0 = blockIdx.x * 128, n0 = blockIdx.y * 128;
  const short* Ap = (MODE == 0) ? A + (size_t)b * NPOS * K : A;
  const short* Bp = (MODE == 0) ? Bm : Bm + (size_t)b * NPOS * K;

  __shared__ short As[128 * 64], Bs[128 * 64];
  int t = threadIdx.x;
  int lane = t & 63, wid = t >> 6;
  int wm = wid >> 1, wn = wid & 1;
  f32x4 acc[4][4] = {};

  for (int kt = 0; kt < 4; ++kt) {
    int k0 = kt * 64;
    short8 av[4], bv[4];
    #pragma unroll
    for (int p = 0; p < 4; ++p) {
      int ci = t + p * 256;
      int row = ci >> 3, ch = ci & 7;
      av[p] = *(const short8*)(Ap + (size_t)(m0 + row) * K + k0 + ch * 8);
      bv[p] = *(const short8*)(Bp + (size_t)(n0 + row) * K + k0 + ch * 8);
    }
    __syncthreads();
    #pragma unroll
    for (int p = 0; p < 4; ++p) {
      int ci = t + p * 256;
      int row = ci >> 3, ch = ci & 7;
      int off = (row * 128 + ch * 16) ^ ((row & 7) << 4);
      *(short8*)((char*)As + off) = av[p];
      *(short8*)((char*)Bs + off) = bv[p];
    }
    __syncthreads();
    #pragma unroll
    for (int ks = 0; ks < 2; ++ks) {
      short8 af[4], bf[4];
      int inner = ks * 64 + (lane >> 4) * 16;
      #pragma unroll
      for (int mi = 0; mi < 4; ++mi) {
        int row = wm * 64 + mi * 16 + (lane & 15);
        af[mi] = *(short8*)((char*)As + ((row * 128 + inner) ^ ((row & 7) << 4)));
      }
      #pragma unroll
      for (int ni = 0; ni < 4; ++ni) {
        int row = wn * 64 + ni * 16 + (lane & 15);
        bf[ni] = *(short8*)((char*)Bs + ((row * 128 + inner) ^ ((row & 7) << 4)));
      }
      #pragma unroll
      for (int mi = 0; mi < 4; ++mi)
        #pragma unroll
        for (int ni = 0; ni < 4; ++ni)
          acc[mi][ni] = __builtin_amdgcn_mfma_f32_16x16x32_bf16(af[mi], bf[ni], acc[mi][ni], 0, 0, 0);
    }
  }

  #pragma unroll
  for (int mi = 0; mi < 4; ++mi)
    #pragma unroll
    for (int ni = 0; ni < 4; ++ni) {
      int gcol = n0 + wn * 64 + ni * 16 + (lane & 15);
      #pragma unroll
      for (int r = 0; r < 4; ++r) {
        int grow = m0 + wm * 64 + mi * 16 + (lane >> 4) * 4 + r;
        if (MODE == 0) {
          float v = acc[mi][ni][r] + bias[gcol];
          short h = f2b(v);
          if (gcol < 256)       qb[((size_t)b * NPOS + grow) * DIM + gcol] = h;
          else if (gcol < 512)  kb[((size_t)b * NPOS + grow) * DIM + gcol - 256] = h;
          else                  vtb[((size_t)b * DIM + gcol - 512) * NPOS + grow] = h;
        } else {
          float v = acc[mi][ni][r] + bias[grow];
          size_t idx = ((size_t)b * DIM + grow) * NPOS + gcol;
          outf[idx] = v + resid[idx];
        }
      }
    }
}

// ---- flash v5: Q_wave=32 (2 subtiles), 4 waves = 2 q-wave-pairs x 2 kv-halves, KVBLK=32.
// global_load_lds staging (dbuf, 1 barrier/iter), linear K rows + XOR-pre-swizzled source.
// LDS (140288 B): K[buf][h] @ buf*32768+h*16384 (32x512B rows, data swizzled ^((row&7)<<4));
//   V[buf][h] @ 65536+buf*32768+h*16384 ([256d][32kv], 64B rows);
//   P @ 131072 + wid*2048 + u*1024; lm @ 139264. Combine scratch aliases [0,64K).
__launch_bounds__(256, 1)
__global__ void k_flash(const short* __restrict__ qb, const short* __restrict__ kb,
                        const short* __restrict__ vtb, short* __restrict__ ob) {
  __shared__ __align__(16) char smem[140288];
  float* lm = (float*)(smem + 139264);
  float* scratch = (float*)smem;

  // XCD-aware decode: xcd = i&7 -> batch b = xcd>>1 (one batch's KV per L2 pair)
  int i = blockIdx.x;
  int xcd = i & 7, slot = i >> 3;
  int b = xcd >> 1;
  int bx = slot * 2 + (xcd & 1);   // 0..63
  int q0 = bx * 64;

  int t = threadIdx.x, lane = t & 63, g = lane >> 4, q = lane & 15, wid = t >> 6;
  int qs = wid & 1, h = wid >> 1;

  const short* kbB = kb + (size_t)b * NPOS * DIM;
  const short* vbB = vtb + (size_t)b * DIM * NPOS;

  // ---- Q fragments (B-operand of swapped QK^T), 2 subtiles, pre-scaled by 1/16 ----
  short8 qf[2][8];
  #pragma unroll
  for (int u = 0; u < 2; ++u) {
    int qrow = q0 + qs * 32 + u * 16 + q;
    const short* qp = qb + ((size_t)b * NPOS + qrow) * DIM + g * 8;
    #pragma unroll
    for (int s = 0; s < 8; ++s) {
      short8 v = *(const short8*)(qp + s * 32);
      #pragma unroll
      for (int j = 0; j < 8; ++j) {
        float f = __uint_as_float(((unsigned)(unsigned short)v[j]) << 16) * 0.0625f;
        v[j] = f2b(f);
      }
      qf[u][s] = v;
    }
  }

  // ---- staging source pointers (per thread, it=0) ----
  unsigned su = h * 16384u + qs * 8192u;   // uniform LDS sub-offset
  const short* srcK[8];
  const short* srcV[8];
  {
    int l5 = lane >> 5, l31 = lane & 31;
    #pragma unroll
    for (int j = 0; j < 8; ++j) {
      int r = qs * 16 + j * 2 + l5;
      int colb = (l31 * 16) ^ (((j * 2 + l5) & 7) << 4);
      srcK[j] = kbB + (size_t)(h * 2048 + r) * DIM + (colb >> 1);
      srcV[j] = vbB + (size_t)(qs * 128 + j * 16 + (lane >> 2)) * NPOS + h * 2048 + (lane & 3) * 8;
    }
  }

  char* Pb = smem + 131072 + wid * 2048;
  char* prow0 = Pb + q * 64;

  f32x4 oacc[2][16] = {};
  float mS[2] = {-1e30f, -1e30f}, lS[2] = {0.f, 0.f};

  const int NIT = 64;
  int buf = 0;
  // prologue: stage tile 0 into buf0
  #pragma unroll
  for (int j = 0; j < 8; ++j) {
    gl16(srcK[j], smem + su + j * 1024u);
    gl16(srcV[j], smem + 65536u + su + j * 1024u);
  }
  __syncthreads();

  for (int it = 0; it < NIT; ++it) {
    // stage next tile into buf^1 (DMA latency hides under this iter's compute)
    if (it + 1 < NIT) {
      size_t ko = (size_t)(it + 1) * 32 * DIM;
      int vo = (it + 1) * 32;
      unsigned nb = (unsigned)(buf ^ 1) * 32768u + su;
      #pragma unroll
      for (int j = 0; j < 8; ++j) {
        gl16(srcK[j] + ko, smem + nb + j * 1024u);
        gl16(srcV[j] + vo, smem + 65536u + nb + j * 1024u);
      }
    }

    // ---- QK^T (swapped): S^T[32kv x 16q] per subtile, scale folded into Q ----
    const char* kl = smem + (unsigned)buf * 32768u + h * 16384u;
    int xr = (q & 7) << 4;
    f32x4 sacc[2][2] = {};   // [t2][u]
    #pragma unroll
    for (int s = 0; s < 8; ++s) {
      #pragma unroll
      for (int t2 = 0; t2 < 2; ++t2) {
        short8 kf = *(const short8*)(kl + (t2 * 16 + q) * 512 + ((s * 64 + g * 16) ^ xr));
        sacc[t2][0] = __builtin_amdgcn_mfma_f32_16x16x32_bf16(kf, qf[0][s], sacc[t2][0], 0, 0, 0);
        sacc[t2][1] = __builtin_amdgcn_mfma_f32_16x16x32_bf16(kf, qf[1][s], sacc[t2][1], 0, 0, 0);
      }
    }

    // ---- online softmax per subtile, in-lane (q = lane&15), defer-max THR=8 ----
    #pragma unroll
    for (int u = 0; u < 2; ++u) {
      float s0 = sacc[0][u][0], s1 = sacc[0][u][1], s2 = sacc[0][u][2], s3 = sacc[0][u][3];
      float s4 = sacc[1][u][0], s5 = sacc[1][u][1], s6 = sacc[1][u][2], s7 = sacc[1][u][3];
      float mx = fmaxf(fmaxf(fmaxf(s0, s1), fmaxf(s2, s3)), fmaxf(fmaxf(s4, s5), fmaxf(s6, s7)));
      mx = fmaxf(mx, __shfl_xor(mx, 16, 64));
      mx = fmaxf(mx, __shfl_xor(mx, 32, 64));
      if (!__all(mx <= mS[u] + 8.f)) {
        float mn = fmaxf(mS[u], mx);
        float al = __expf(mS[u] - mn);
        mS[u] = mn; lS[u] *= al;
        #pragma unroll
        for (int r = 0; r < 4; ++r) {
          float ar = __shfl(al, (lane & 48) + ((lane & 48) >> 2) + r, 64);
          #pragma unroll
          for (int nt = 0; nt < 16; ++nt) oacc[u][nt][r] *= ar;
        }
      }
      float p0 = __expf(s0 - mS[u]), p1 = __expf(s1 - mS[u]);
      float p2 = __expf(s2 - mS[u]), p3 = __expf(s3 - mS[u]);
      float p4 = __expf(s4 - mS[u]), p5 = __expf(s5 - mS[u]);
      float p6 = __expf(s6 - mS[u]), p7 = __expf(s7 - mS[u]);
      float ts = ((p0 + p1) + (p2 + p3)) + ((p4 + p5) + (p6 + p7));
      ts += __shfl_xor(ts, 16, 64);
      ts += __shfl_xor(ts, 32, 64);
      lS[u] += ts;
      unsigned w0, w1, w2, w3;
      asm("v_cvt_pk_bf16_f32 %0, %1, %2" : "=v"(w0) : "v"(p0), "v"(p1));
      asm("v_cvt_pk_bf16_f32 %0, %1, %2" : "=v"(w1) : "v"(p2), "v"(p3));
      asm("v_cvt_pk_bf16_f32 %0, %1, %2" : "=v"(w2) : "v"(p4), "v"(p5));
      asm("v_cvt_pk_bf16_f32 %0, %1, %2" : "=v"(w3) : "v"(p6), "v"(p7));
      *(short4v*)(prow0 + u * 1024 + g * 8)      = __builtin_bit_cast(short4v, (u32x2){w0, w1});
      *(short4v*)(prow0 + u * 1024 + 32 + g * 8) = __builtin_bit_cast(short4v, (u32x2){w2, w3});
    }
    asm volatile("" ::: "memory");   // pin P stores before the pa loads

    // ---- PV: O[32q x 256d] += P[32q x 32kv] * V[32kv x 256d]; V-frags shared by both u ----
    short8 pa0 = *(short8*)(prow0 + q * 0 + g * 16);          // u=0
    short8 pa1 = *(short8*)(prow0 + 1024 + g * 16);           // u=1
    const char* vl = smem + 65536u + (unsigned)buf * 32768u + h * 16384u;
    #pragma unroll
    for (int nt = 0; nt < 16; ++nt) {
      short8 vf = *(const short8*)(vl + (nt * 16 + q) * 64 + g * 16);
      oacc[0][nt] = __builtin_amdgcn_mfma_f32_16x16x32_bf16(pa0, vf, oacc[0][nt], 0, 0, 0);
      oacc[1][nt] = __builtin_amdgcn_mfma_f32_16x16x32_bf16(pa1, vf, oacc[1][nt], 0, 0, 0);
    }
    __syncthreads();   // next tile staged & visible; prev reads done
    buf ^= 1;
  }

  // ---- combine the two kv-halves (per q-wave-pair qs, per subtile u) ----
  if (lane < 16) {
    #pragma unroll
    for (int u = 0; u < 2; ++u) {
      lm[(wid * 32 + u * 16 + lane) * 2]     = mS[u];
      lm[(wid * 32 + u * 16 + lane) * 2 + 1] = lS[u];
    }
  }
  __syncthreads();
  int pw = wid ^ 2;
  float alr[2][4], iLr[2][4];
  #pragma unroll
  for (int u = 0; u < 2; ++u) {
    float mo = lm[(pw * 32 + u * 16 + q) * 2];
    float lo = lm[(pw * 32 + u * 16 + q) * 2 + 1];
    float M = fmaxf(mS[u], mo);
    float al = __expf(mS[u] - M);
    float Lf = lS[u] * al + lo * __expf(mo - M);
    #pragma unroll
    for (int r = 0; r < 4; ++r) {
      int src = (lane & 48) + ((lane & 48) >> 2) + r;
      alr[u][r] = __shfl(al, src, 64);
      iLr[u][r] = 1.f / __shfl(Lf, src, 64);
    }
  }
  __syncthreads();  // K/V dbuf now dead -> scratch
  if (h == 0) {
    #pragma unroll
    for (int u = 0; u < 2; ++u) {
      float* sc = scratch + (qs * 2 + u) * 4096;
      #pragma unroll
      for (int nt = 0; nt < 16; ++nt)
        #pragma unroll
        for (int r = 0; r < 4; ++r) {
          int ql = 4 * g + r;
          int col = nt * 16 + q;
          sc[(ql * 256 + col) ^ ((g & 1) << 4)] = oacc[u][nt][r] * alr[u][r];
        }
    }
  }
  __syncthreads();
  if (h == 1) {
    #pragma unroll
    for (int u = 0; u < 2; ++u) {
      float* sc = scratch + (qs * 2 + u) * 4096;
      #pragma unroll
      for (int nt = 0; nt < 16; ++nt)
        #pragma unroll
        for (int r = 0; r < 4; ++r) {
          int ql = 4 * g + r;
          int col = nt * 16 + q;
          float v = (sc[(ql * 256 + col) ^ ((g & 1) << 4)] + oacc[u][nt][r] * alr[u][r]) * iLr[u][r];
          ob[((size_t)b * NPOS + q0 + qs * 32 + u * 16 + ql) * DIM + col] = f2b(v);
        }
    }
  }
}

extern "C" void kernel_launch(void* const* d_in, const int* in_sizes, int n_in,
                              void* d_out, int out_size, void* d_ws, size_t ws_size,
                              hipStream_t stream) {
  const float* x     = (const float*)d_in[0];
  const float* gamma = (const float*)d_in[1];
  const float* beta  = (const float*)d_in[2];
  const float* wqkv  = (const float*)d_in[3];
  const float* bqkv  = (const float*)d_in[4];
  const float* wproj = (const float*)d_in[5];
  const float* bproj = (const float*)d_in[6];
  float* out = (float*)d_out;

  char* ws = (char*)d_ws;
  float* stats = (float*)ws;
  short* wqb = (short*)(ws + 1024);
  short* wpb = (short*)(ws + 1024 + 393216);
  size_t off = 1024 + 393216 + 131072;
  const size_t SZ = (size_t)NB * NPOS * DIM * sizeof(short);  // 8 MB
  short* ht   = (short*)(ws + off); off += SZ;
  short* qbuf = (short*)(ws + off); off += SZ;
  short* kbuf = (short*)(ws + off); off += SZ;
  short* vtb  = (short*)(ws + off); off += SZ;
  short* obuf = ht;  // h_t dead after QKV gemm; reuse for attention output

  k_convert_w<<<768, 256, 0, stream>>>(wqkv, wproj, wqb, wpb);
  k_gn_stats<<<128, 256, 0, stream>>>(x, stats);
  k_gn_apply<<<dim3(4, 64, NB), 256, 0, stream>>>(x, stats, gamma, beta, ht);
  k_gemm<0><<<dim3(32, 6, NB), 256, 0, stream>>>(ht, wqb, bqkv, qbuf, kbuf, vtb, nullptr, nullptr);
  k_flash<<<dim3(256), 256, 0, stream>>>(qbuf, kbuf, vtb, obuf);
  k_gemm<1><<<dim3(2, 32, NB), 256, 0, stream>>>(wpb, obuf, bproj, nullptr, nullptr, nullptr, x, out);
}

// Round 8
// 176.585 us; speedup vs baseline: 2.8613x; 1.1355x over previous
//
#include <hip/hip_runtime.h>
#include <stdint.h>

#define DIM 256
#define NPOS 4096
#define NB 4
#define GROUPS 32

typedef __attribute__((ext_vector_type(8))) short short8;
typedef __attribute__((ext_vector_type(4))) short short4v;
typedef __attribute__((ext_vector_type(4))) float f32x4;
typedef __attribute__((ext_vector_type(16))) float f32x16;
typedef __attribute__((ext_vector_type(2))) unsigned int u32x2;
typedef __attribute__((ext_vector_type(4))) unsigned int u32x4;

__device__ __forceinline__ short f2b(float f) {
  unsigned u = __float_as_uint(f);
  unsigned r = (u + 0x7fffu + ((u >> 16) & 1u)) >> 16;
  return (short)r;
}

__device__ __forceinline__ void gl16(const short* g, char* lds) {
  __builtin_amdgcn_global_load_lds((const __attribute__((address_space(1))) void*)g,
                                   (__attribute__((address_space(3))) void*)lds, 16, 0, 0);
}

// ---------------- weight conversion (f32 -> bf16) ----------------
__global__ void k_convert_w(const float* __restrict__ wq, const float* __restrict__ wp,
                            short* __restrict__ wqb, short* __restrict__ wpb) {
  int i = blockIdx.x * 256 + threadIdx.x;
  if (i < 768 * 256) wqb[i] = f2b(wq[i]);
  if (i < 256 * 256) wpb[i] = f2b(wp[i]);
}

// ---------------- GroupNorm stats: one block per (b,g) ----------------
__global__ void k_gn_stats(const float* __restrict__ x, float* __restrict__ stats) {
  int bg = blockIdx.x;
  const float4* b4 = (const float4*)(x + (size_t)bg * 8 * NPOS);
  float s = 0.f, ss = 0.f;
  for (int i = threadIdx.x; i < 8192; i += 256) {
    float4 v = b4[i];
    s  += v.x + v.y + v.z + v.w;
    ss += v.x * v.x + v.y * v.y + v.z * v.z + v.w * v.w;
  }
  #pragma unroll
  for (int m = 1; m < 64; m <<= 1) { s += __shfl_xor(s, m, 64); ss += __shfl_xor(ss, m, 64); }
  __shared__ float red[8];
  int wid = threadIdx.x >> 6;
  if ((threadIdx.x & 63) == 0) { red[wid * 2] = s; red[wid * 2 + 1] = ss; }
  __syncthreads();
  if (threadIdx.x == 0) {
    float S = red[0] + red[2] + red[4] + red[6];
    float SS = red[1] + red[3] + red[5] + red[7];
    float mean = S / 32768.f;
    float var = SS / 32768.f - mean * mean;
    stats[bg * 2] = mean;
    stats[bg * 2 + 1] = rsqrtf(var + 1e-6f);
  }
}

// ------------- GroupNorm apply + transpose: x(B,C,N) f32 -> h_t(B,N,C) bf16 -------------
__global__ void k_gn_apply(const float* __restrict__ x, const float* __restrict__ stats,
                           const float* __restrict__ gamma, const float* __restrict__ beta,
                           short* __restrict__ ht) {
  int ct = blockIdx.x, nt = blockIdx.y, b = blockIdx.z;
  int c0 = ct * 64, n0 = nt * 64;
  __shared__ short lt[64 * 72];
  int t = threadIdx.x;
  #pragma unroll
  for (int p = 0; p < 4; ++p) {
    int row = (t >> 4) + p * 16;
    int colb = (t & 15) * 4;
    int c = c0 + row;
    float mean = stats[(b * GROUPS + (c >> 3)) * 2];
    float rstd = stats[(b * GROUPS + (c >> 3)) * 2 + 1];
    float ga = gamma[c], be = beta[c];
    float4 v = *(const float4*)(x + ((size_t)(b * DIM + c)) * NPOS + n0 + colb);
    short4v o;
    o.x = f2b((v.x - mean) * rstd * ga + be);
    o.y = f2b((v.y - mean) * rstd * ga + be);
    o.z = f2b((v.z - mean) * rstd * ga + be);
    o.w = f2b((v.w - mean) * rstd * ga + be);
    *(short4v*)&lt[row * 72 + colb] = o;
  }
  __syncthreads();
  #pragma unroll
  for (int p = 0; p < 2; ++p) {
    int nr = (t >> 3) + p * 32;
    int ch = t & 7;
    short8 o;
    #pragma unroll
    for (int j = 0; j < 8; ++j) o[j] = lt[(ch * 8 + j) * 72 + nr];
    *(short8*)(ht + ((size_t)(b * NPOS + n0 + nr)) * DIM + c0 + ch * 8) = o;
  }
}

// ---------------- gemm_bt: C[M,N] = A[M,K] * B[N,K]^T, K=256, 128x128 tile ----------------
template <int MODE>
__launch_bounds__(256, 2)
__global__ void k_gemm(const short* __restrict__ A, const short* __restrict__ Bm,
                       const float* __restrict__ bias,
                       short* __restrict__ qb, short* __restrict__ kb, short* __restrict__ vtb,
                       const float* __restrict__ resid, float* __restrict__ outf) {
  const int K = 256;
  int b = blockIdx.z;
  int m0 = blockIdx.x * 128, n0 = blockIdx.y * 128;
  const short* Ap = (MODE == 0) ? A + (size_t)b * NPOS * K : A;
  const short* Bp = (MODE == 0) ? Bm : Bm + (size_t)b * NPOS * K;

  __shared__ short As[128 * 64], Bs[128 * 64];
  int t = threadIdx.x;
  int lane = t & 63, wid = t >> 6;
  int wm = wid >> 1, wn = wid & 1;
  f32x4 acc[4][4] = {};

  for (int kt = 0; kt < 4; ++kt) {
    int k0 = kt * 64;
    short8 av[4], bv[4];
    #pragma unroll
    for (int p = 0; p < 4; ++p) {
      int ci = t + p * 256;
      int row = ci >> 3, ch = ci & 7;
      av[p] = *(const short8*)(Ap + (size_t)(m0 + row) * K + k0 + ch * 8);
      bv[p] = *(const short8*)(Bp + (size_t)(n0 + row) * K + k0 + ch * 8);
    }
    __syncthreads();
    #pragma unroll
    for (int p = 0; p < 4; ++p) {
      int ci = t + p * 256;
      int row = ci >> 3, ch = ci & 7;
      int off = (row * 128 + ch * 16) ^ ((row & 7) << 4);
      *(short8*)((char*)As + off) = av[p];
      *(short8*)((char*)Bs + off) = bv[p];
    }
    __syncthreads();
    #pragma unroll
    for (int ks = 0; ks < 2; ++ks) {
      short8 af[4], bf[4];
      int inner = ks * 64 + (lane >> 4) * 16;
      #pragma unroll
      for (int mi = 0; mi < 4; ++mi) {
        int row = wm * 64 + mi * 16 + (lane & 15);
        af[mi] = *(short8*)((char*)As + ((row * 128 + inner) ^ ((row & 7) << 4)));
      }
      #pragma unroll
      for (int ni = 0; ni < 4; ++ni) {
        int row = wn * 64 + ni * 16 + (lane & 15);
        bf[ni] = *(short8*)((char*)Bs + ((row * 128 + inner) ^ ((row & 7) << 4)));
      }
      #pragma unroll
      for (int mi = 0; mi < 4; ++mi)
        #pragma unroll
        for (int ni = 0; ni < 4; ++ni)
          acc[mi][ni] = __builtin_amdgcn_mfma_f32_16x16x32_bf16(af[mi], bf[ni], acc[mi][ni], 0, 0, 0);
    }
  }

  #pragma unroll
  for (int mi = 0; mi < 4; ++mi)
    #pragma unroll
    for (int ni = 0; ni < 4; ++ni) {
      int gcol = n0 + wn * 64 + ni * 16 + (lane & 15);
      #pragma unroll
      for (int r = 0; r < 4; ++r) {
        int grow = m0 + wm * 64 + mi * 16 + (lane >> 4) * 4 + r;
        if (MODE == 0) {
          float v = acc[mi][ni][r] + bias[gcol];
          short h = f2b(v);
          if (gcol < 256)       qb[((size_t)b * NPOS + grow) * DIM + gcol] = h;
          else if (gcol < 512)  kb[((size_t)b * NPOS + grow) * DIM + gcol - 256] = h;
          else                  vtb[((size_t)b * DIM + gcol - 512) * NPOS + grow] = h;
        } else {
          float v = acc[mi][ni][r] + bias[grow];
          size_t idx = ((size_t)b * DIM + grow) * NPOS + gcol;
          outf[idx] = v + resid[idx];
        }
      }
    }
}

// ---- flash v6b: 32x32x16 MFMA, in-register P (cvt_pk + permlane32_swap), KVBLK=32.
// 4 waves = 2 q-pairs(32 rows) x 2 kv-halves(2048). gl16 dbuf staging, 1 barrier/iter.
// S^T = mfma(K, Q): lane owns q=lane&31, 16 kv in regs -> softmax fully in-lane.
// PV: O = mfma(V^T-frag, P-frag): lane owns q, regs = d. No P LDS at all.
// permlane32_swap(first, second): first.upper32 <-> second.lower32. With
// w_j = pack(p[2j],p[2j+1]) (reg r ~ kv=(r&3)+8*(r>>2)+4*hi): swap(w0,w2) makes
// w0 = {hi0:(kv0,1), hi1:(kv8,9)} = pf0.word0 and w2 = {(4,5),(12,13)} = pf0.word2.
// LDS (131072): K[buf][h]@buf*32768+h*16384 (32x512B rows, swz ^((row&7)<<4));
//   V[buf][h]@65536+buf*32768+h*16384 ([256d][32kv] 64B rows, swz ^((row&6)<<3)).
// Epilogue aliases: sc32@0 (f32, 257w stride), sc16@66560 (short, 258 stride), lm@100352.
__launch_bounds__(256, 1)
__global__ void k_flash(const short* __restrict__ qb, const short* __restrict__ kb,
                        const short* __restrict__ vtb, short* __restrict__ ob) {
  __shared__ __align__(16) char smem[131072];

  int i = blockIdx.x;
  int xcd = i & 7, slot = i >> 3;
  int b = xcd >> 1;
  int bx = slot * 2 + (xcd & 1);   // 0..63
  int q0 = bx * 64;

  int t = threadIdx.x, lane = t & 63, wid = t >> 6;
  int q = lane & 31, hi = lane >> 5;
  int qs = wid & 1, h = wid >> 1;

  const short* kbB = kb + (size_t)b * NPOS * DIM;
  const short* vbB = vtb + (size_t)b * DIM * NPOS;

  // ---- Q fragments (B-operand, 32x32x16: row=lane&31, k=hi*8+[0..7]), pre-scaled 1/16 ----
  short8 qf[16];
  {
    int qrow = q0 + qs * 32 + q;
    const short* qp = qb + ((size_t)b * NPOS + qrow) * DIM + hi * 8;
    #pragma unroll
    for (int s = 0; s < 16; ++s) {
      short8 v = *(const short8*)(qp + s * 16);
      #pragma unroll
      for (int j = 0; j < 8; ++j) {
        float f = __uint_as_float(((unsigned)(unsigned short)v[j]) << 16) * 0.0625f;
        v[j] = f2b(f);
      }
      qf[s] = v;
    }
  }

  // ---- staging source pointers (pre-swizzled global columns; LDS dest linear) ----
  unsigned su = h * 16384u + qs * 8192u;
  const short* srcK[8];
  const short* srcV[8];
  {
    int l5 = lane >> 5, l31 = lane & 31;
    #pragma unroll
    for (int j = 0; j < 8; ++j) {
      int r = qs * 16 + j * 2 + l5;
      int colb = (l31 * 16) ^ ((r & 7) << 4);
      srcK[j] = kbB + (size_t)(h * 2048 + r) * DIM + (colb >> 1);
      int vr = qs * 128 + j * 16 + (lane >> 2);
      int vcol = ((lane & 3) * 16) ^ ((vr & 6) << 3);
      srcV[j] = vbB + (size_t)vr * NPOS + h * 2048 + (vcol >> 1);
    }
  }

  f32x16 oacc[8] = {};
  float m = -1e30f, l = 0.f;

  const int NIT = 64;
  int buf = 0;
  // prologue: stage tile 0 into buf0
  #pragma unroll
  for (int j = 0; j < 8; ++j) {
    gl16(srcK[j], smem + su + j * 1024u);
    gl16(srcV[j], smem + 65536u + su + j * 1024u);
  }
  __syncthreads();

  const unsigned kx = (unsigned)((q & 7) << 4);
  const unsigned vx = (unsigned)((q & 6) << 3);

  for (int it = 0; it < NIT; ++it) {
    // stage next tile into buf^1 (latency hides under this iter's compute)
    if (it + 1 < NIT) {
      size_t ko = (size_t)(it + 1) * 32 * DIM;
      int vo = (it + 1) * 32;
      unsigned nb = (unsigned)(buf ^ 1) * 32768u + su;
      #pragma unroll
      for (int j = 0; j < 8; ++j) {
        gl16(srcK[j] + ko, smem + nb + j * 1024u);
        gl16(srcV[j] + vo, smem + 65536u + nb + j * 1024u);
      }
    }

    // ---- QK^T (swapped): one 32x32 S^T tile, scale folded into Q ----
    const char* kl = smem + (unsigned)buf * 32768u + h * 16384u;
    const char* vl = smem + 65536u + (unsigned)buf * 32768u + h * 16384u;
    f32x16 sacc = {};
    #pragma unroll
    for (int s = 0; s < 16; ++s) {
      short8 kf = *(const short8*)(kl + q * 512u + ((s * 32u + hi * 16u) ^ kx));
      sacc = __builtin_amdgcn_mfma_f32_32x32x16_bf16(kf, qf[s], sacc, 0, 0, 0);
    }

    // ---- online softmax fully in-lane (lane owns q; 16 kv here + 16 at partner) ----
    float mx = sacc[0];
    #pragma unroll
    for (int r = 1; r < 16; ++r) mx = fmaxf(mx, sacc[r]);
    mx = fmaxf(mx, __shfl_xor(mx, 32, 64));
    if (!__all(mx <= m + 8.f)) {
      float mn = fmaxf(m, mx);
      float al = __expf(m - mn);
      m = mn; l *= al;
      #pragma unroll
      for (int dt = 0; dt < 8; ++dt)
        #pragma unroll
        for (int r = 0; r < 16; ++r) oacc[dt][r] *= al;
    }
    float p_[16];
    float ts = 0.f;
    #pragma unroll
    for (int r = 0; r < 16; ++r) { p_[r] = __expf(sacc[r] - m); ts += p_[r]; }
    ts += __shfl_xor(ts, 32, 64);
    l += ts;

    // ---- P -> bf16 A-frag entirely in registers (T12) ----
    unsigned w0, w1, w2, w3, w4, w5, w6, w7;
    asm("v_cvt_pk_bf16_f32 %0, %1, %2" : "=v"(w0) : "v"(p_[0]),  "v"(p_[1]));
    asm("v_cvt_pk_bf16_f32 %0, %1, %2" : "=v"(w1) : "v"(p_[2]),  "v"(p_[3]));
    asm("v_cvt_pk_bf16_f32 %0, %1, %2" : "=v"(w2) : "v"(p_[4]),  "v"(p_[5]));
    asm("v_cvt_pk_bf16_f32 %0, %1, %2" : "=v"(w3) : "v"(p_[6]),  "v"(p_[7]));
    asm("v_cvt_pk_bf16_f32 %0, %1, %2" : "=v"(w4) : "v"(p_[8]),  "v"(p_[9]));
    asm("v_cvt_pk_bf16_f32 %0, %1, %2" : "=v"(w5) : "v"(p_[10]), "v"(p_[11]));
    asm("v_cvt_pk_bf16_f32 %0, %1, %2" : "=v"(w6) : "v"(p_[12]), "v"(p_[13]));
    asm("v_cvt_pk_bf16_f32 %0, %1, %2" : "=v"(w7) : "v"(p_[14]), "v"(p_[15]));
    asm("v_permlane32_swap_b32 %0, %1" : "+v"(w0), "+v"(w2));
    asm("v_permlane32_swap_b32 %0, %1" : "+v"(w1), "+v"(w3));
    asm("v_permlane32_swap_b32 %0, %1" : "+v"(w4), "+v"(w6));
    asm("v_permlane32_swap_b32 %0, %1" : "+v"(w5), "+v"(w7));
    short8 pf0 = __builtin_bit_cast(short8, (u32x4){w0, w1, w2, w3});  // kv 0..15
    short8 pf1 = __builtin_bit_cast(short8, (u32x4){w4, w5, w6, w7});  // kv 16..31

    // ---- PV: oacc[dt] += mfma(V^T-frag(d rows), P-frag(q rows)) ----
    #pragma unroll
    for (int dt = 0; dt < 8; ++dt) {
      unsigned vrow = (dt * 32u + q) * 64u;
      short8 vf0 = *(const short8*)(vl + vrow + ((hi * 16u) ^ vx));
      short8 vf1 = *(const short8*)(vl + vrow + ((32u + hi * 16u) ^ vx));
      oacc[dt] = __builtin_amdgcn_mfma_f32_32x32x16_bf16(vf0, pf0, oacc[dt], 0, 0, 0);
      oacc[dt] = __builtin_amdgcn_mfma_f32_32x32x16_bf16(vf1, pf1, oacc[dt], 0, 0, 0);
    }
    __syncthreads();   // next tile staged & visible; all reads of buf done
    buf ^= 1;
  }

  // ---- combine the two kv-halves; everything per-lane (q-local) ----
  float* lmm = (float*)(smem + 100352);
  float* lml = lmm + 128;
  if (lane < 32) { lmm[(qs * 2 + h) * 32 + q] = m; lml[(qs * 2 + h) * 32 + q] = l; }
  __syncthreads();
  float mo = lmm[(qs * 2 + (h ^ 1)) * 32 + q];
  float lo = lml[(qs * 2 + (h ^ 1)) * 32 + q];
  float M = fmaxf(m, mo);
  float al = __expf(m - M);
  float Lf = l * al + lo * __expf(mo - M);
  float iL = 1.f / Lf;

  float* sc32 = (float*)smem;                // [qs][32 q][257w] f32
  short* sc16 = (short*)(smem + 66560);      // [qs][32 q][258]  bf16
  if (h == 0) {
    #pragma unroll
    for (int dt = 0; dt < 8; ++dt)
      #pragma unroll
      for (int r = 0; r < 16; ++r) {
        int d = dt * 32 + (r & 3) + 8 * (r >> 2) + 4 * hi;
        sc32[qs * 8224 + q * 257 + d] = oacc[dt][r] * al;
      }
  }
  __syncthreads();
  if (h == 1) {
    #pragma unroll
    for (int dt = 0; dt < 8; ++dt)
      #pragma unroll
      for (int r = 0; r < 16; ++r) {
        int d = dt * 32 + (r & 3) + 8 * (r >> 2) + 4 * hi;
        float v = (sc32[qs * 8224 + q * 257 + d] + oacc[dt][r] * al) * iL;
        sc16[qs * 8256 + q * 258 + d] = f2b(v);
      }
  }
  __syncthreads();
  // cooperative coalesced copy to global
  {
    int row = t >> 2;                        // 0..63 = qs*32+q
    const short* src = sc16 + (row >> 5) * 8256 + (row & 31) * 258 + (t & 3) * 64;
    short* dst = ob + ((size_t)b * NPOS + q0 + row) * DIM + (t & 3) * 64;
    #pragma unroll
    for (int j = 0; j < 8; ++j)
      *(short8*)(dst + j * 8) = *(const short8*)(src + j * 8);
  }
}

extern "C" void kernel_launch(void* const* d_in, const int* in_sizes, int n_in,
                              void* d_out, int out_size, void* d_ws, size_t ws_size,
                              hipStream_t stream) {
  const float* x     = (const float*)d_in[0];
  const float* gamma = (const float*)d_in[1];
  const float* beta  = (const float*)d_in[2];
  const float* wqkv  = (const float*)d_in[3];
  const float* bqkv  = (const float*)d_in[4];
  const float* wproj = (const float*)d_in[5];
  const float* bproj = (const float*)d_in[6];
  float* out = (float*)d_out;

  char* ws = (char*)d_ws;
  float* stats = (float*)ws;
  short* wqb = (short*)(ws + 1024);
  short* wpb = (short*)(ws + 1024 + 393216);
  size_t off = 1024 + 393216 + 131072;
  const size_t SZ = (size_t)NB * NPOS * DIM * sizeof(short);  // 8 MB
  short* ht   = (short*)(ws + off); off += SZ;
  short* qbuf = (short*)(ws + off); off += SZ;
  short* kbuf = (short*)(ws + off); off += SZ;
  short* vtb  = (short*)(ws + off); off += SZ;
  short* obuf = ht;  // h_t dead after QKV gemm; reuse for attention output

  k_convert_w<<<768, 256, 0, stream>>>(wqkv, wproj, wqb, wpb);
  k_gn_stats<<<128, 256, 0, stream>>>(x, stats);
  k_gn_apply<<<dim3(4, 64, NB), 256, 0, stream>>>(x, stats, gamma, beta, ht);
  k_gemm<0><<<dim3(32, 6, NB), 256, 0, stream>>>(ht, wqb, bqkv, qbuf, kbuf, vtb, nullptr, nullptr);
  k_flash<<<dim3(256), 256, 0, stream>>>(qbuf, kbuf, vtb, obuf);
  k_gemm<1><<<dim3(2, 32, NB), 256, 0, stream>>>(wpb, obuf, bproj, nullptr, nullptr, nullptr, x, out);
}